// Round 1
// baseline (165.414 us; speedup 1.0000x reference)
//
#include <hip/hip_runtime.h>
#include <math.h>

// Problem constants: BSZ=64, BEAM=8, VOCAB=50257, STEP=5
// R10: same algorithm as R9/R6 (phase-1 chunked sort + minimal phase 2), but
// the 13-load burst is now FORCED. R9's rocprof showed VGPR_Count=36 — the
// compiler had re-rolled the "13 independent float4s in registers" into
// serialized small batches (52 floats cannot live in 36 VGPRs), leaving
// per-wave MLP ~1 and rowtop latency-bound at 1.69 TB/s effective (61 us,
// invariant to L3 warmth, VALUBusy 7%). Fix: load as ext_vector f32x4 and
// pin all 13 vectors (+tail scalar) with one asm volatile "+v" barrier
// between load issue and the max tree. This forces all loads in flight
// before the first consume AND forbids rematerialization in the owner-scan
// (values are asm outputs, not load results). launch_bounds(512,4) allows
// 128 VGPRs/thread, so ~90 VGPRs still fits at 4 waves/SIMD.
#define BSZ   64
#define BEAM  8
#define VOCAB 50257
#define NSTEP 5
#define K     16
#define DIV_RATE 0.5f
#define N4    (VOCAB / 4)        // 12564 float4s (+1 tail scalar)
#define SEGF4 (N4 / 2)           // 6282 float4 per half-row (exact split)
#define REM   (SEGF4 - 12 * 512) // 138: threads with tid<REM do a 13th load
#define SBUF_CAP 1024            // candidate LDS cap (proof bound 16*53=848)

typedef unsigned long long u64;
typedef unsigned u32;
typedef float f32x4 __attribute__((ext_vector_type(4)));

// order-preserving float<->uint (monotone for all non-NaN)
__device__ __forceinline__ u32 f2s(float f) {
    u32 u = __float_as_uint(f);
    return (u & 0x80000000u) ? ~u : (u | 0x80000000u);
}
__device__ __forceinline__ float s2f(u32 s) {
    u32 u = (s & 0x80000000u) ? (s ^ 0x80000000u) : ~s;
    return __uint_as_float(u);
}

// wave(64)-wide max of a u64 key (validated R1-R9)
__device__ __forceinline__ u64 wmax64(u64 k) {
#pragma unroll
    for (int off = 32; off > 0; off >>= 1) {
        u32 lo = __shfl_xor((u32)k, off, 64);
        u32 hi = __shfl_xor((u32)(k >> 32), off, 64);
        u64 o = ((u64)hi << 32) | lo;
        if (o > k) k = o;
    }
    return k;
}

#define BSTEPS(X)                                                            \
    X(2, 1)                                                                  \
    X(4, 2)  X(4, 1)                                                         \
    X(8, 4)  X(8, 2)  X(8, 1)                                                \
    X(16, 8) X(16, 4) X(16, 2) X(16, 1)                                      \
    X(32, 16) X(32, 8) X(32, 4) X(32, 2) X(32, 1)                            \
    X(64, 32) X(64, 16) X(64, 8) X(64, 4) X(64, 2) X(64, 1)

// u32 ascending bitonic sort across 64 lanes (validated R3-R9)
__device__ __forceinline__ u32 bitonic64_asc(u32 v, int lane) {
#define BS32(K_, J_)                                                         \
    {                                                                        \
        u32 o = __shfl_xor(v, (J_), 64);                                     \
        bool tmin = ((lane & (J_)) == 0) == ((lane & (K_)) == 0);            \
        v = tmin ? (v < o ? v : o) : (v > o ? v : o);                        \
    }
    BSTEPS(BS32)
#undef BS32
    return v;
}

// u64 ascending bitonic sort across 64 lanes (same network, 2 shfl/step)
__device__ __forceinline__ u64 bitonic64_asc_u64(u64 v, int lane) {
#define BS64(K_, J_)                                                         \
    {                                                                        \
        u32 lo = __shfl_xor((u32)v, (J_), 64);                               \
        u32 hi = __shfl_xor((u32)(v >> 32), (J_), 64);                       \
        u64 o = ((u64)hi << 32) | lo;                                        \
        bool tmin = ((lane & (J_)) == 0) == ((lane & (K_)) == 0);            \
        v = tmin ? (v < o ? v : o) : (v > o ? v : o);                        \
    }
    BSTEPS(BS64)
#undef BS64
    return v;
}

// Phase 1: one block per (half-row). 13 independent float4 loads/thread kept
// live in registers (FORCED via asm pin — see header); T = exact 16th
// largest of the 512 per-thread maxima (3-level bitonic tournament); owner
// threads (m >= T) scan registers into an LDS candidate list; wave 0
// extracts the sorted half-row top-16 via chunked u64 bitonic and writes 16
// keys densely. key = f2s(value)<<32 | ~vocab_idx (bias deferred: uniform
// per row).
__global__ __launch_bounds__(512, 4) void rowtop(
    const float* __restrict__ lprobs, u64* __restrict__ segk)
{
    const int tid  = threadIdx.x;
    const int lane = tid & 63;
    const int wave = tid >> 6;       // 0..7
    const int seg  = blockIdx.x;     // 0..1
    const int row  = blockIdx.y;     // 0..511

    const f32x4* rp4  = (const f32x4*)(lprobs + (size_t)row * VOCAB);
    const f32x4* base = rp4 + seg * SEGF4 + tid;

    // ---- burst: 12 unconditional + 1 predicated, all independent ----
    f32x4 a0  = base[0];
    f32x4 a1  = base[512];
    f32x4 a2  = base[1024];
    f32x4 a3  = base[1536];
    f32x4 a4  = base[2048];
    f32x4 a5  = base[2560];
    f32x4 a6  = base[3072];
    f32x4 a7  = base[3584];
    f32x4 a8  = base[4096];
    f32x4 a9  = base[4608];
    f32x4 a10 = base[5120];
    f32x4 a11 = base[5632];
    f32x4 a12 = {-INFINITY, -INFINITY, -INFINITY, -INFINITY};
    if (tid < REM) a12 = base[6144];
    float extra = -INFINITY;                    // vocab tail element 50256
    if (seg == 1 && tid == 0) extra = ((const float*)rp4)[VOCAB - 1];

    // Pin all loads live here: forces all 13 vmem ops issued before the
    // first consume (full MLP) and makes the values non-rematerializable
    // for the owner-scan phase below.
    asm volatile(""
                 : "+v"(a0), "+v"(a1), "+v"(a2), "+v"(a3), "+v"(a4),
                   "+v"(a5), "+v"(a6), "+v"(a7), "+v"(a8), "+v"(a9),
                   "+v"(a10), "+v"(a11), "+v"(a12), "+v"(extra));

#define MAX4(v) fmaxf(fmaxf((v).x, (v).y), fmaxf((v).z, (v).w))
    float m = fmaxf(
        fmaxf(fmaxf(fmaxf(MAX4(a0), MAX4(a1)), fmaxf(MAX4(a2), MAX4(a3))),
              fmaxf(fmaxf(MAX4(a4), MAX4(a5)), fmaxf(MAX4(a6), MAX4(a7)))),
        fmaxf(fmaxf(fmaxf(MAX4(a8), MAX4(a9)), fmaxf(MAX4(a10), MAX4(a11))),
              fmaxf(MAX4(a12), extra)));
#undef MAX4

    __shared__ u32 smax[128];        // 8 waves x top-16 maxima
    __shared__ u32 sfin[32];         // 2 x top-16 finalists
    __shared__ u32 sT;
    __shared__ u64 sbuf[SBUF_CAP];
    __shared__ int scnt;
    if (tid == 0) scnt = 0;

    // ---- level 1: per-wave top-16 of lane maxima ----
    u32 v0 = bitonic64_asc(f2s(m), lane);
    if (lane >= 48) smax[wave * 16 + (lane - 48)] = v0;
    __syncthreads();

    // ---- level 2: waves 0,1 each reduce 64 survivors -> 16 finalists ----
    if (wave < 2) {
        u32 w = bitonic64_asc(smax[wave * 64 + lane], lane);
        if (lane >= 48) sfin[wave * 16 + (lane - 48)] = w;
    }
    __syncthreads();

    // ---- level 3: wave 0 sorts 32 finalists; lane 48 = 16th largest ----
    if (wave == 0) {
        u32 w = bitonic64_asc(lane < 32 ? sfin[lane] : 0u, lane);
        if (lane == 48) sT = w;
    }
    __syncthreads();
    const float T = s2f(sT);

    // ---- owners (m >= T) scan their REGISTERS into LDS ----
#define APPEND(vv, ei)                                                       \
    if ((vv) >= T) {                                                         \
        int p = atomicAdd(&scnt, 1);                                         \
        if (p < SBUF_CAP) sbuf[p] = ((u64)f2s(vv) << 32) | (u32)~(u32)(ei);  \
    }
#define APP4(av, c4)                                                         \
    {                                                                        \
        int b4 = 4 * (seg * SEGF4 + (c4) * 512 + tid);                       \
        APPEND((av).x, b4 + 0) APPEND((av).y, b4 + 1)                        \
        APPEND((av).z, b4 + 2) APPEND((av).w, b4 + 3)                        \
    }
    if (m >= T) {
        APP4(a0, 0)  APP4(a1, 1)  APP4(a2, 2)   APP4(a3, 3)
        APP4(a4, 4)  APP4(a5, 5)  APP4(a6, 6)   APP4(a7, 7)
        APP4(a8, 8)  APP4(a9, 9)  APP4(a10, 10) APP4(a11, 11)
        APP4(a12, 12)                              // -INF lanes never pass
        APPEND(extra, VOCAB - 1)                   // -INF unless set
    }
#undef APP4
#undef APPEND
    __syncthreads();

    // ---- wave 0: sorted top-16 of candidates via chunked u64 bitonic ----
    if (wave == 0) {
        const int n = min(scnt, SBUF_CAP);        // n >= 16 always
        u64 run = 0;
        for (int b0 = 0; b0 < n; b0 += 48) {
            u64 v = run;                          // lanes 48..63 keep top-16
            if (lane < 48) { int p = b0 + lane; v = (p < n) ? sbuf[p] : 0; }
            v = bitonic64_asc_u64(v, lane);
            run = (lane >= 48) ? v : 0;
        }
        if (lane >= 48) {                         // rank 0 = best
            int r = 63 - lane;
            segk[((size_t)row * 2 + seg) * K + r] = run;
        }
    }
}

// Phase 2: block b, wave j: merge beam j's two sorted 16-lists (one u64
// bitonic over 32 keys + 32 zero pads; rank = lane position), apply bias +
// sibling penalty, wave 0 runs the validated 128->16 extraction.
__global__ __launch_bounds__(512) void finalize(
    const u64* __restrict__ segk, const float* __restrict__ scores,
    const int* __restrict__ step_ptr, float* __restrict__ out)
{
    const int tid  = threadIdx.x;
    const int lane = tid & 63;
    const int j    = tid >> 6;       // beam 0..7
    const int b    = blockIdx.x;
    const int row  = b * BEAM + j;
    const int step = *step_ptr;

    __shared__ u64 fkey[BEAM * K];
    __shared__ int fvid[BEAM * K];

    // merged row top-16: sort 32 real keys (unique: disjoint vocab halves)
    u64 v = (lane < 32) ? segk[(size_t)row * 32 + lane] : 0ull;
    v = bitonic64_asc_u64(v, lane);
    // lanes 48..63 hold the row top-16 ascending; rank r = 63 - lane

    float* out_s = out;
    float* out_i = out + BSZ * K;
    float* out_b = out + 2 * BSZ * K;

    if (step == 0) {
        // reference: top_k(lprobs[:,0,:]): idx%vocab=idx, idx//vocab=0
        if (j == 0 && lane >= 48) {
            int r = 63 - lane;
            out_s[b * K + r] = s2f((u32)(v >> 32));
            out_i[b * K + r] = (float)(int)~(u32)v;
            out_b[b * K + r] = 0.0f;
        }
        return;
    }

    if (lane >= 48) {
        int r = 63 - lane;
        float val = s2f((u32)(v >> 32));
        float add = scores[row * NSTEP + step - 1];
        float sc  = val + add - (float)(r + 1) * DIV_RATE;
        int c = j * K + r;
        fkey[c] = ((u64)f2s(sc) << 32) | (u32)(127 - c);  // lower c wins ties
        fvid[c] = (int)~(u32)v;
    }
    __syncthreads();

    if (tid < 64) {
        u64 pa = fkey[lane];
        u64 pb = fkey[lane + 64];
        u64 m2 = 0;
#pragma unroll 1
        for (int it = 0; it < K; ++it) {
            u64 mm = wmax64(pa > pb ? pa : pb);
            if (lane == it) m2 = mm;
            if (pa == mm) pa = 0; else if (pb == mm) pb = 0;
        }
        if (lane < K) {
            int c = 127 - (int)(m2 & 0xFFFFFFFFull);
            out_s[b * K + lane] = s2f((u32)(m2 >> 32));
            out_i[b * K + lane] = (float)fvid[c];
            out_b[b * K + lane] = (float)(c >> 4);
        }
    }
}

extern "C" void kernel_launch(void* const* d_in, const int* in_sizes, int n_in,
                              void* d_out, int out_size, void* d_ws, size_t ws_size,
                              hipStream_t stream) {
    const float* lprobs = (const float*)d_in[0];
    const float* scores = (const float*)d_in[1];
    const int*   step   = (const int*)d_in[2];

    u64* segk = (u64*)d_ws;   // 512 rows * 2 segs * 16 keys * 8 B = 128 KB

    dim3 g1(2, BSZ * BEAM);
    rowtop<<<g1, 512, 0, stream>>>(lprobs, segk);
    finalize<<<BSZ, 512, 0, stream>>>(segk, scores, step, (float*)d_out);
}